// Round 15
// baseline (388.870 us; speedup 1.0000x reference)
//
#include <hip/hip_runtime.h>
#include <math.h>

#define BB 8
#define FF 256
#define SS 1024
#define KK 16
#define ITERS 5

typedef unsigned long long ull;

// SESSION LEDGER (measured):
// R12 coop grid.sync: 94us/barrier -> multi-launch only.
// R10 64x64/wave: occupancy collapse, dist 147us.
// R5  64x64/block 2-wave barriers: dist 124us. R8 pair-barriers: 119.6us.
// R8  cost+update last-block fusion: ~70us/iter. REVERTED (loop = R4 form).
// R13 32x32 wave-private depth-2: dist 95.0us, VALUBusy 66.75%, occ 26.5%,
//     conflicts 0. 66.75% == 2048 VALU cyc / 3072 LDS-pipe cyc per
//     CU-chunk (16 waves x 16 ds_read_b128 x 12cyc vs 4 SIMD x 4 x 512):
//     dist is LDS-ISSUE-bound. Fix: A operand global->VGPR (8-way lane
//     broadcast), halving ds_read count. B stays LDS-staged.

// ---------- wm stage 1: partial column sums of w ----------
#define ICH 8
__global__ void wm_part_kernel(const float* __restrict__ w, float* __restrict__ part) {
    int j = blockIdx.x * 256 + threadIdx.x;
    int ic = blockIdx.y, b = blockIdx.z;
    const float* wp = w + (size_t)b * SS * SS + (size_t)ic * (SS / ICH) * SS + j;
    float s = 0.f;
#pragma unroll 16
    for (int i = 0; i < SS / ICH; ++i) s += wp[(size_t)i * SS];
    part[((size_t)ic * BB + b) * SS + j] = s;
}

// ---------- d[b][i][j] = sum_f |x[b][f][i] - x[b][f][j]| ----------
// R14: 32x32 wave-private tiles (2 waves/block, no barriers, 4224 waves).
// B: LDS depth-2 staged (4 bufs x 1KB/wave). A: registers, ping-pong
// prefetch (aA/aB, 8 float4 each), loaded straight from global (8 lanes
// share each addr -> broadcast). Per chunk/lane: 8 ds_read_b128 (was 16)
// -> LDS pipe 1536 cyc/CU-chunk < VALU 2048 -> VALU-bound.
// vmcnt ledger: steady 18 in flight [B(c+1),A(c)x8,B(c+2),A(c+1)x8];
// vmcnt(9) retires through A(c). Epilogue 17 -> vmcnt(8) -> vmcnt(0).
// Same values, f ascending -> d bitwise identical to all passing runs.
#define FCD 8
#define TS 32
#define NT (SS / TS)
__device__ __forceinline__ void async_copy16(const float* g, const float* s) {
    __builtin_amdgcn_global_load_lds((const __attribute__((address_space(1))) void*)g,
                                     (__attribute__((address_space(3))) void*)s, 16, 0, 0);
}

__global__ __launch_bounds__(128, 4) void dist_kernel(const float* __restrict__ x,
                                                      float* __restrict__ d) {
    __shared__ float smem[2048];   // per wave (1024): 4 bufs x [B 256]
    int tid = threadIdx.x;
    int wave = tid >> 6, lane = tid & 63;
    int b = blockIdx.y;
    int w = blockIdx.x * 2 + wave;      // 0..527 triangular tile id (32x32 tiles)
    int it = 0, rem = w;
    while (rem >= NT - it) { rem -= NT - it; ++it; }
    int jt = it + rem;
    int i0 = it * TS, j0 = jt * TS;
    const float* xb = x + (size_t)b * FF * SS;
    float* db = d + (size_t)b * SS * SS;
    float* wbase = smem + wave * 1024;
    int ly = lane >> 3, lx = lane & 7;           // 8x8 lane grid, 4x4 each
    int sFl = lane >> 3, sTk = (lane & 7) * 4;   // staging: 8 f-rows x 32 tok/inst
    const float* aRow = xb + i0 + ly * 4;        // this lane's A row segment

    float acc[4][4] = {};
    float4 aA[8], aB[8];

    auto stageB = [&](int c) {
        float* B = wbase + (c & 3) * 256;
        async_copy16(xb + ((size_t)c * FCD + sFl) * SS + j0 + sTk, B);
    };
    auto loadA = [&](int c, float4 (&aX)[8]) {
#pragma unroll
        for (int f = 0; f < FCD; ++f)
            aX[f] = *(const float4*)(aRow + ((size_t)c * FCD + f) * SS);
    };
    auto compute = [&](int c, const float4 (&aX)[8]) {
        const float* B = wbase + (c & 3) * 256;
#pragma unroll
        for (int f = 0; f < FCD; ++f) {
            float4 bb = *(const float4*)(B + f * 32 + lx * 4);
            float av[4] = {aX[f].x, aX[f].y, aX[f].z, aX[f].w};
            float bv[4] = {bb.x, bb.y, bb.z, bb.w};
#pragma unroll
            for (int r = 0; r < 4; ++r)
#pragma unroll
                for (int cc = 0; cc < 4; ++cc)
                    acc[r][cc] += fabsf(av[r] - bv[cc]);
        }
    };

    stageB(0); stageB(1);
    loadA(0, aA);                       // in flight: B0,B1,A0x8 = 10
#pragma unroll 1
    for (int c = 0; c <= 28; c += 2) {
        // WAR: buf (c+2)&3 last read by compute(c-2), ds_reads retired
        asm volatile("s_waitcnt lgkmcnt(0)" ::: "memory");
        stageB(c + 2);
        loadA(c + 1, aB);
        asm volatile("s_waitcnt vmcnt(9)" ::: "memory");   // B(c),A(c) landed
        compute(c, aA);
        asm volatile("s_waitcnt lgkmcnt(0)" ::: "memory");
        stageB(c + 3);
        loadA(c + 2, aA);
        asm volatile("s_waitcnt vmcnt(9)" ::: "memory");   // B(c+1),A(c+1) landed
        compute(c + 1, aB);
    }
    // after loop: 9 in flight = [B(31), A(30)x8]
    loadA(31, aB);                                         // 17
    asm volatile("s_waitcnt vmcnt(8)" ::: "memory");       // B(31),A(30) landed
    compute(30, aA);
    asm volatile("s_waitcnt vmcnt(0)" ::: "memory");
    compute(31, aB);

    // direct tile: rows i0+ly*4+r, cols j0+lx*4
#pragma unroll
    for (int r = 0; r < 4; ++r) {
        float4 v = make_float4(acc[r][0], acc[r][1], acc[r][2], acc[r][3]);
        *(float4*)&db[(size_t)(i0 + ly * 4 + r) * SS + j0 + lx * 4] = v;
    }
    if (it != jt) {
        // mirror straight from registers (d bitwise symmetric)
#pragma unroll
        for (int c = 0; c < 4; ++c) {
            float4 v = make_float4(acc[0][c], acc[1][c], acc[2][c], acc[3][c]);
            *(float4*)&db[(size_t)(j0 + lx * 4 + c) * SS + i0 + ly * 4] = v;
        }
    }
}

// ---------- wm finalize + topk (jax.lax.top_k) + initial assign, fused ----------
// wm > 0 strictly (means of uniform[0,1)), so float bits are order-monotonic.
__global__ __launch_bounds__(1024) void topk_assign_kernel(const float* __restrict__ part,
                                                           float* __restrict__ wm,
                                                           const float* __restrict__ d,
                                                           int* __restrict__ assign) {
    int b = blockIdx.x;
    int tid = threadIdx.x;          // == token index
    int lane = tid & 63, wv = tid >> 6;
    __shared__ ull red[16];
    __shared__ int ctr_s[KK];
    float v = 0.f;
#pragma unroll
    for (int ic = 0; ic < ICH; ++ic) v += part[((size_t)ic * BB + b) * SS + tid];
    v *= (1.0f / SS);
    wm[b * SS + tid] = v;
    ull key = (((ull)__float_as_uint(v)) << 32) | (ull)(0xFFFFFFFFu - (unsigned)tid);
    for (int k = 0; k < KK; ++k) {
        ull kk = key;
#pragma unroll
        for (int off = 32; off; off >>= 1) {
            ull o = __shfl_down(kk, off, 64);
            if (o > kk) kk = o;
        }
        if (lane == 0) red[wv] = kk;
        __syncthreads();
        if (wv == 0) {
            ull k2 = (lane < 16) ? red[lane] : 0ull;
#pragma unroll
            for (int off = 8; off; off >>= 1) {
                ull o = __shfl_down(k2, off, 64);
                if (o > k2) k2 = o;
            }
            if (lane == 0) red[0] = k2;
        }
        __syncthreads();
        ull W = red[0];
        int widx = (int)(0xFFFFFFFFu - (unsigned)(W & 0xFFFFFFFFu));
        if (tid == widx) key = 0;
        if (tid == 0) ctr_s[k] = widx;
        __syncthreads();
    }
    const float* db = d + (size_t)b * SS * SS;
    float bv = INFINITY;
    int bk = 0;
#pragma unroll
    for (int k = 0; k < KK; ++k) {
        float vv = db[(size_t)ctr_s[k] * SS + tid];
        if (vv < bv) { bv = vv; bk = k; }
    }
    assign[b * SS + tid] = bk;
}

// ---------- cost[b][i] = sum_{j: assign[j]==assign[i]} d[i][j]*wm[j] ----------
// 16 rows per block: wm+assign cached in LDS once, 4 waves x 4 rows,
// barrier-free per-row wave reduction. (R4 measured-good form.)
#define RPB 16
__global__ __launch_bounds__(256) void cost_kernel(const float* __restrict__ d,
                                                   const float* __restrict__ wm,
                                                   const int* __restrict__ assign,
                                                   float* __restrict__ cost) {
    int b = blockIdx.y;
    int tid = threadIdx.x;
    int lane = tid & 63, wv = tid >> 6;
    __shared__ float wmv[SS];
    __shared__ int asg[SS];
    *(float4*)&wmv[tid * 4] = *(const float4*)&wm[b * SS + tid * 4];
    *(int4*)&asg[tid * 4] = *(const int4*)&assign[b * SS + tid * 4];
    __syncthreads();
    const float* db = d + (size_t)b * SS * SS;
#pragma unroll
    for (int r = 0; r < RPB / 4; ++r) {
        int i = blockIdx.x * RPB + wv * (RPB / 4) + r;
        int my = asg[i];
        const float* drow = db + (size_t)i * SS;
        float s = 0.f;
#pragma unroll
        for (int c = 0; c < SS / 256; ++c) {      // 4 sweeps of 64 lanes x float4
            int j = c * 256 + lane * 4;
            float4 dv = *(const float4*)&drow[j];
            float4 wv4 = *(const float4*)&wmv[j];
            int4 a4 = *(const int4*)&asg[j];
            s += (a4.x == my) ? dv.x * wv4.x : 0.f;
            s += (a4.y == my) ? dv.y * wv4.y : 0.f;
            s += (a4.z == my) ? dv.z * wv4.z : 0.f;
            s += (a4.w == my) ? dv.w * wv4.w : 0.f;
        }
#pragma unroll
        for (int off = 32; off; off >>= 1) s += __shfl_down(s, off, 64);
        if (lane == 0) cost[b * SS + i] = s;
    }
}

// ---------- medoid update (+ next assign, or final gather), widened ----------
// grid (4, B): each block redundantly computes all K medoids (cheap 8 KB
// LDS scan), then handles a 256-token quarter of the assign (or gather).
// (R4 measured-good form; 4096 threads/batch for the update phase.)
__global__ __launch_bounds__(1024) void update_assign_kernel(
        const float* __restrict__ d, const float* __restrict__ cost,
        int* __restrict__ assign, const float* __restrict__ x,
        float* __restrict__ out, int last) {
    int b = blockIdx.y;
    int q = blockIdx.x;             // quarter 0..3
    int tid = threadIdx.x;
    int lane = tid & 63, wv = tid >> 6;
    __shared__ float cost_s[SS];
    __shared__ int assign_s[SS];
    __shared__ int ctr_s[KK];
    __shared__ ull pk[4][256];
    cost_s[tid] = cost[b * SS + tid];
    assign_s[tid] = assign[b * SS + tid];
    __syncthreads();
    ull best = ~0ull;
    int k = wv;   // 16 waves, 16 clusters
    for (int c = 0; c < SS / 64; ++c) {
        int i = c * 64 + lane;
        if (assign_s[i] == k) {
            ull key = (((ull)__float_as_uint(cost_s[i])) << 32) | (unsigned)i;
            if (key < best) best = key;
        }
    }
#pragma unroll
    for (int off = 32; off; off >>= 1) {
        ull o = __shfl_down(best, off, 64);
        if (o < best) best = o;
    }
    if (lane == 0) ctr_s[k] = (best == ~0ull) ? 0 : (int)(best & 0xFFFFFFFFu);
    __syncthreads();
    const float* db = d + (size_t)b * SS * SS;
    if (!last) {
        int tok = q * 256 + (tid & 255);
        int g = tid >> 8;
        ull bk = ~0ull;
#pragma unroll
        for (int kk = 0; kk < 4; ++kk) {
            int k2 = g * 4 + kk;
            float vv = db[(size_t)ctr_s[k2] * SS + tok];
            ull key = (((ull)__float_as_uint(vv)) << 32) | (unsigned)k2;
            if (key < bk) bk = key;
        }
        pk[g][tid & 255] = bk;
        __syncthreads();
        if (tid < 256) {
            ull m = pk[0][tid];
            if (pk[1][tid] < m) m = pk[1][tid];
            if (pk[2][tid] < m) m = pk[2][tid];
            if (pk[3][tid] < m) m = pk[3][tid];
            assign[b * SS + q * 256 + tid] = (int)(m & 0xFFFFFFFFu);
        }
    } else {
        int e = q * 1024 + tid;     // FF*KK = 4096 elements total
        int f = e / KK, k2 = e % KK;
        out[((size_t)b * FF + f) * KK + k2] = x[((size_t)b * FF + f) * SS + ctr_s[k2]];
    }
}

extern "C" void kernel_launch(void* const* d_in, const int* in_sizes, int n_in,
                              void* d_out, int out_size, void* d_ws, size_t ws_size,
                              hipStream_t stream) {
    const float* x = (const float*)d_in[0];   // [B,F,S]
    const float* w = (const float*)d_in[1];   // [B,S,S]
    float* out = (float*)d_out;               // [B,F,K]

    char* ws = (char*)d_ws;
    float* d = (float*)ws;                              // B*S*S floats = 33.55 MB
    size_t off = (size_t)BB * SS * SS * sizeof(float);
    float* wm = (float*)(ws + off);   off += (size_t)BB * SS * sizeof(float);
    int* assign = (int*)(ws + off);   off += (size_t)BB * SS * sizeof(int);
    float* cost = (float*)(ws + off); off += (size_t)BB * SS * sizeof(float);
    float* part = (float*)(ws + off); // [ICH][B][S] = 256 KB (non-aliasing:
                                      // consumed by topk AFTER dist runs)

    // dist first, wm_part second — independent; wm_part backfills the tail.
    // 528 triangular 32x32 wave-tiles per batch, 2 waves (2 tiles) per block.
    dist_kernel<<<dim3(264, BB), 128, 0, stream>>>(x, d);
    wm_part_kernel<<<dim3(SS / 256, ICH, BB), 256, 0, stream>>>(w, part);
    topk_assign_kernel<<<BB, 1024, 0, stream>>>(part, wm, d, assign);
    for (int itr = 0; itr < ITERS; ++itr) {
        cost_kernel<<<dim3(SS / RPB, BB), 256, 0, stream>>>(d, wm, assign, cost);
        update_assign_kernel<<<dim3(4, BB), 1024, 0, stream>>>(d, cost, assign, x, out,
                                                               itr == ITERS - 1 ? 1 : 0);
    }
}

// Round 17
// 227.745 us; speedup vs baseline: 1.7075x; 1.7075x over previous
//
#include <hip/hip_runtime.h>
#include <math.h>

#define BB 8
#define FF 256
#define SS 1024
#define KK 16
#define ITERS 5

typedef unsigned long long ull;

// SESSION LEDGER (measured):
// R12 coop grid.sync: 94us/barrier -> multi-launch only.
// R10 64x64/wave: occupancy collapse, dist 147us.
// R5/R8 barrier'd variants: 124/119.6us (lockstep stalls).
// R8 cost+update last-block fusion: ~70us/iter. REVERTED.
// R13 32x32 wave-private depth-2: dist 95.0us BEST, VALUBusy 66.75% ==
//     2048 VALU cyc / 3072 LDS-pipe cyc per CU-chunk -> LDS-issue-bound.
// R14 A-in-VGPR (aA/aB 8xfloat4 ping-pong + asm waits): compiler SPILLED
//     (VGPR_Count 64, WRITE_SIZE 567MB scratch, dist 266us). hipcc won't
//     keep big float4 arrays in regs across asm-volatile pipelines.
//     REVERTED to R13-exact dist. Dist ceiling accepted at ~95us.

// ---------- wm stage 1: partial column sums of w ----------
#define ICH 8
__global__ void wm_part_kernel(const float* __restrict__ w, float* __restrict__ part) {
    int j = blockIdx.x * 256 + threadIdx.x;
    int ic = blockIdx.y, b = blockIdx.z;
    const float* wp = w + (size_t)b * SS * SS + (size_t)ic * (SS / ICH) * SS + j;
    float s = 0.f;
#pragma unroll 16
    for (int i = 0; i < SS / ICH; ++i) s += wp[(size_t)i * SS];
    part[((size_t)ic * BB + b) * SS + j] = s;
}

// ---------- d[b][i][j] = sum_f |x[b][f][i] - x[b][f][j]| ----------
// R13-exact (measured 95.0us): 32x32 wave-private tiles (2 waves/block,
// no barriers, 4224 waves = 4.1/SIMD), 4 private LDS buffers (depth-2
// prefetch, vmcnt(4)). f ascending per element -> d bitwise identical.
#define FCD 8
#define TS 32
#define NT (SS / TS)
__device__ __forceinline__ void async_copy16(const float* g, const float* s) {
    __builtin_amdgcn_global_load_lds((const __attribute__((address_space(1))) void*)g,
                                     (__attribute__((address_space(3))) void*)s, 16, 0, 0);
}

__global__ __launch_bounds__(128, 4) void dist_kernel(const float* __restrict__ x,
                                                      float* __restrict__ d) {
    __shared__ float smem[4096];   // per wave (2048): 4 bufs x [A 256 | B 256]
    int tid = threadIdx.x;
    int wave = tid >> 6, lane = tid & 63;
    int b = blockIdx.y;
    int w = blockIdx.x * 2 + wave;      // 0..527 triangular tile id (32x32 tiles)
    int it = 0, rem = w;
    while (rem >= NT - it) { rem -= NT - it; ++it; }
    int jt = it + rem;
    int i0 = it * TS, j0 = jt * TS;
    const float* xb = x + (size_t)b * FF * SS;
    float* db = d + (size_t)b * SS * SS;
    float* wbase = smem + wave * 2048;
    int ly = lane >> 3, lx = lane & 7;           // 8x8 lane grid, 4x4 each
    int sFl = lane >> 3, sTk = (lane & 7) * 4;   // staging: 8 f-rows x 32 tok/inst

    float acc[4][4] = {};

    auto stage = [&](int c) {
        float* A = wbase + (c & 3) * 512;
        const float* base = xb + ((size_t)c * FCD + sFl) * SS;
        async_copy16(base + i0 + sTk, A);          // A chunk: 8f x 32tok = 1 inst
        async_copy16(base + j0 + sTk, A + 256);    // B chunk
    };
    auto compute = [&](int c) {
        const float* A = wbase + (c & 3) * 512;
        const float* B = A + 256;
#pragma unroll
        for (int f = 0; f < FCD; ++f) {
            float4 a = *(const float4*)(A + f * 32 + ly * 4);
            float4 bb = *(const float4*)(B + f * 32 + lx * 4);
            float av[4] = {a.x, a.y, a.z, a.w};
            float bv[4] = {bb.x, bb.y, bb.z, bb.w};
#pragma unroll
            for (int r = 0; r < 4; ++r)
#pragma unroll
                for (int cc = 0; cc < 4; ++cc)
                    acc[r][cc] += fabsf(av[r] - bv[cc]);
        }
    };

    stage(0); stage(1);                 // 4 loads in flight (depth-2)
#pragma unroll 1
    for (int c = 0; c < FF / FCD - 2; ++c) {
        // WAR: buf (c+2)&3 == (c-2)&3; compute(c-2)'s ds_reads retired
        asm volatile("s_waitcnt lgkmcnt(0)" ::: "memory");
        stage(c + 2);
        // in flight: chunks c+1,c+2 (4 loads); chunk c's 2 have landed
        asm volatile("s_waitcnt vmcnt(4)" ::: "memory");
        compute(c);
    }
    asm volatile("s_waitcnt vmcnt(2)" ::: "memory");
    compute(30);
    asm volatile("s_waitcnt vmcnt(0)" ::: "memory");
    compute(31);

    // direct tile: rows i0+ly*4+r, cols j0+lx*4
#pragma unroll
    for (int r = 0; r < 4; ++r) {
        float4 v = make_float4(acc[r][0], acc[r][1], acc[r][2], acc[r][3]);
        *(float4*)&db[(size_t)(i0 + ly * 4 + r) * SS + j0 + lx * 4] = v;
    }
    if (it != jt) {
        // mirror straight from registers (d bitwise symmetric)
#pragma unroll
        for (int c = 0; c < 4; ++c) {
            float4 v = make_float4(acc[0][c], acc[1][c], acc[2][c], acc[3][c]);
            *(float4*)&db[(size_t)(j0 + lx * 4 + c) * SS + i0 + ly * 4] = v;
        }
    }
}

// ---------- wm finalize + topk (jax.lax.top_k) + initial assign, fused ----------
// wm > 0 strictly (means of uniform[0,1)), so float bits are order-monotonic.
__global__ __launch_bounds__(1024) void topk_assign_kernel(const float* __restrict__ part,
                                                           float* __restrict__ wm,
                                                           const float* __restrict__ d,
                                                           int* __restrict__ assign) {
    int b = blockIdx.x;
    int tid = threadIdx.x;          // == token index
    int lane = tid & 63, wv = tid >> 6;
    __shared__ ull red[16];
    __shared__ int ctr_s[KK];
    float v = 0.f;
#pragma unroll
    for (int ic = 0; ic < ICH; ++ic) v += part[((size_t)ic * BB + b) * SS + tid];
    v *= (1.0f / SS);
    wm[b * SS + tid] = v;
    ull key = (((ull)__float_as_uint(v)) << 32) | (ull)(0xFFFFFFFFu - (unsigned)tid);
    for (int k = 0; k < KK; ++k) {
        ull kk = key;
#pragma unroll
        for (int off = 32; off; off >>= 1) {
            ull o = __shfl_down(kk, off, 64);
            if (o > kk) kk = o;
        }
        if (lane == 0) red[wv] = kk;
        __syncthreads();
        if (wv == 0) {
            ull k2 = (lane < 16) ? red[lane] : 0ull;
#pragma unroll
            for (int off = 8; off; off >>= 1) {
                ull o = __shfl_down(k2, off, 64);
                if (o > k2) k2 = o;
            }
            if (lane == 0) red[0] = k2;
        }
        __syncthreads();
        ull W = red[0];
        int widx = (int)(0xFFFFFFFFu - (unsigned)(W & 0xFFFFFFFFu));
        if (tid == widx) key = 0;
        if (tid == 0) ctr_s[k] = widx;
        __syncthreads();
    }
    const float* db = d + (size_t)b * SS * SS;
    float bv = INFINITY;
    int bk = 0;
#pragma unroll
    for (int k = 0; k < KK; ++k) {
        float vv = db[(size_t)ctr_s[k] * SS + tid];
        if (vv < bv) { bv = vv; bk = k; }
    }
    assign[b * SS + tid] = bk;
}

// ---------- cost[b][i] = sum_{j: assign[j]==assign[i]} d[i][j]*wm[j] ----------
// R16: RPB 16 -> 8 (1024 blocks = 4/CU, was 2/CU): cost is an L3-read
// sweep at thin occupancy; doubling resident waves hides d-row latency.
// Per-row reduction topology unchanged -> bitwise identical cost[].
#define RPB 8
__global__ __launch_bounds__(256) void cost_kernel(const float* __restrict__ d,
                                                   const float* __restrict__ wm,
                                                   const int* __restrict__ assign,
                                                   float* __restrict__ cost) {
    int b = blockIdx.y;
    int tid = threadIdx.x;
    int lane = tid & 63, wv = tid >> 6;
    __shared__ float wmv[SS];
    __shared__ int asg[SS];
    *(float4*)&wmv[tid * 4] = *(const float4*)&wm[b * SS + tid * 4];
    *(int4*)&asg[tid * 4] = *(const int4*)&assign[b * SS + tid * 4];
    __syncthreads();
    const float* db = d + (size_t)b * SS * SS;
#pragma unroll
    for (int r = 0; r < RPB / 4; ++r) {
        int i = blockIdx.x * RPB + wv * (RPB / 4) + r;
        int my = asg[i];
        const float* drow = db + (size_t)i * SS;
        float s = 0.f;
#pragma unroll
        for (int c = 0; c < SS / 256; ++c) {      // 4 sweeps of 64 lanes x float4
            int j = c * 256 + lane * 4;
            float4 dv = *(const float4*)&drow[j];
            float4 wv4 = *(const float4*)&wmv[j];
            int4 a4 = *(const int4*)&asg[j];
            s += (a4.x == my) ? dv.x * wv4.x : 0.f;
            s += (a4.y == my) ? dv.y * wv4.y : 0.f;
            s += (a4.z == my) ? dv.z * wv4.z : 0.f;
            s += (a4.w == my) ? dv.w * wv4.w : 0.f;
        }
#pragma unroll
        for (int off = 32; off; off >>= 1) s += __shfl_down(s, off, 64);
        if (lane == 0) cost[b * SS + i] = s;
    }
}

// ---------- medoid update (+ next assign, or final gather), widened ----------
// grid (4, B): each block redundantly computes all K medoids (cheap 8 KB
// LDS scan), then handles a 256-token quarter of the assign (or gather).
// (R4 measured-good form; 4096 threads/batch for the update phase.)
__global__ __launch_bounds__(1024) void update_assign_kernel(
        const float* __restrict__ d, const float* __restrict__ cost,
        int* __restrict__ assign, const float* __restrict__ x,
        float* __restrict__ out, int last) {
    int b = blockIdx.y;
    int q = blockIdx.x;             // quarter 0..3
    int tid = threadIdx.x;
    int lane = tid & 63, wv = tid >> 6;
    __shared__ float cost_s[SS];
    __shared__ int assign_s[SS];
    __shared__ int ctr_s[KK];
    __shared__ ull pk[4][256];
    cost_s[tid] = cost[b * SS + tid];
    assign_s[tid] = assign[b * SS + tid];
    __syncthreads();
    ull best = ~0ull;
    int k = wv;   // 16 waves, 16 clusters
    for (int c = 0; c < SS / 64; ++c) {
        int i = c * 64 + lane;
        if (assign_s[i] == k) {
            ull key = (((ull)__float_as_uint(cost_s[i])) << 32) | (unsigned)i;
            if (key < best) best = key;
        }
    }
#pragma unroll
    for (int off = 32; off; off >>= 1) {
        ull o = __shfl_down(best, off, 64);
        if (o < best) best = o;
    }
    if (lane == 0) ctr_s[k] = (best == ~0ull) ? 0 : (int)(best & 0xFFFFFFFFu);
    __syncthreads();
    const float* db = d + (size_t)b * SS * SS;
    if (!last) {
        int tok = q * 256 + (tid & 255);
        int g = tid >> 8;
        ull bk = ~0ull;
#pragma unroll
        for (int kk = 0; kk < 4; ++kk) {
            int k2 = g * 4 + kk;
            float vv = db[(size_t)ctr_s[k2] * SS + tok];
            ull key = (((ull)__float_as_uint(vv)) << 32) | (unsigned)k2;
            if (key < bk) bk = key;
        }
        pk[g][tid & 255] = bk;
        __syncthreads();
        if (tid < 256) {
            ull m = pk[0][tid];
            if (pk[1][tid] < m) m = pk[1][tid];
            if (pk[2][tid] < m) m = pk[2][tid];
            if (pk[3][tid] < m) m = pk[3][tid];
            assign[b * SS + q * 256 + tid] = (int)(m & 0xFFFFFFFFu);
        }
    } else {
        int e = q * 1024 + tid;     // FF*KK = 4096 elements total
        int f = e / KK, k2 = e % KK;
        out[((size_t)b * FF + f) * KK + k2] = x[((size_t)b * FF + f) * SS + ctr_s[k2]];
    }
}

extern "C" void kernel_launch(void* const* d_in, const int* in_sizes, int n_in,
                              void* d_out, int out_size, void* d_ws, size_t ws_size,
                              hipStream_t stream) {
    const float* x = (const float*)d_in[0];   // [B,F,S]
    const float* w = (const float*)d_in[1];   // [B,S,S]
    float* out = (float*)d_out;               // [B,F,K]

    char* ws = (char*)d_ws;
    float* d = (float*)ws;                              // B*S*S floats = 33.55 MB
    size_t off = (size_t)BB * SS * SS * sizeof(float);
    float* wm = (float*)(ws + off);   off += (size_t)BB * SS * sizeof(float);
    int* assign = (int*)(ws + off);   off += (size_t)BB * SS * sizeof(int);
    float* cost = (float*)(ws + off); off += (size_t)BB * SS * sizeof(float);
    float* part = (float*)(ws + off); // [ICH][B][S] = 256 KB (non-aliasing:
                                      // consumed by topk AFTER dist runs)

    // dist first, wm_part second — independent; wm_part backfills the tail.
    // 528 triangular 32x32 wave-tiles per batch, 2 waves (2 tiles) per block.
    dist_kernel<<<dim3(264, BB), 128, 0, stream>>>(x, d);
    wm_part_kernel<<<dim3(SS / 256, ICH, BB), 256, 0, stream>>>(w, part);
    topk_assign_kernel<<<BB, 1024, 0, stream>>>(part, wm, d, assign);
    for (int itr = 0; itr < ITERS; ++itr) {
        cost_kernel<<<dim3(SS / RPB, BB), 256, 0, stream>>>(d, wm, assign, cost);
        update_assign_kernel<<<dim3(4, BB), 1024, 0, stream>>>(d, cost, assign, x, out,
                                                               itr == ITERS - 1 ? 1 : 0);
    }
}